// Round 7
// baseline (71.090 us; speedup 1.0000x reference)
//
#include <hip/hip_runtime.h>

#define B 32
#define L 200
#define DIN 64
#define H 64
#define A 36

typedef __attribute__((ext_vector_type(8))) short short8;   // bf16 MFMA fragment
typedef __attribute__((ext_vector_type(4))) float floatx4;  // MFMA accumulator
typedef __attribute__((ext_vector_type(8))) float floatx8;

static __device__ __forceinline__ short f2bf(float f) {
    union { float f; unsigned u; } v; v.f = f;
    unsigned r = (v.u + 0x7FFF + ((v.u >> 16) & 1)) >> 16;  // RNE
    return (short)r;
}
static __device__ __forceinline__ float bf2f(short s) {
    union { unsigned u; float f; } v; v.u = ((unsigned)(unsigned short)s) << 16;
    return v.f;
}

// Kernel 1: h = x@ln_w + ln_b ; h f32, hb16 pre-swizzled, cc = h@w1b.
// Block 0 also reorders w1a/w1c into MFMA-fragment order (f32).
__global__ __launch_bounds__(256) void prep_kernel(
    const float* __restrict__ x, const float* __restrict__ ln_w,
    const float* __restrict__ ln_b, const float* __restrict__ w1,
    float* __restrict__ h_out, float* __restrict__ cc_out, short* __restrict__ hb16_out,
    float* __restrict__ w1a_r, float* __restrict__ w1c_r)
{
    int wave = threadIdx.x >> 6;
    int lane = threadIdx.x & 63;
    int bl = __builtin_amdgcn_readfirstlane(blockIdx.x * 4 + wave);
    const float* xr = x + (size_t)bl * DIN;
    float p0 = ln_b[lane], p1 = 0.f;
    #pragma unroll
    for (int d = 0; d < DIN; d += 2) {
        p0 = fmaf(xr[d],     ln_w[d * H + lane],       p0);   // xr uniform -> s_load
        p1 = fmaf(xr[d + 1], ln_w[(d + 1) * H + lane], p1);
    }
    float acc = p0 + p1;
    __shared__ float hrow[4][H];
    hrow[wave][lane] = acc;
    h_out[(size_t)bl * H + lane] = acc;
    int j = bl % L;
    hb16_out[(size_t)bl * H + (lane ^ ((j & 7) << 3))] = f2bf(acc);
    if (lane < A) {
        float s0 = 0.f, s1 = 0.f;
        #pragma unroll
        for (int hh = 0; hh < H; hh += 2) {
            s0 = fmaf(hrow[wave][hh],     w1[(H + hh) * A + lane],     s0);   // w1b
            s1 = fmaf(hrow[wave][hh + 1], w1[(H + hh + 1) * A + lane], s1);
        }
        cc_out[(size_t)bl * A + lane] = s0 + s1;
    }
    if (blockIdx.x == 0) {
        // fragment-order tables: idx = ((s*3+n)*64 + lane)*8 + e
        for (int idx = threadIdx.x; idx < 2 * 3 * 64 * 8; idx += 256) {
            int e = idx & 7, ln = (idx >> 3) & 63, sn = idx >> 9;
            int s = sn / 3, n = sn - 3 * s;
            int k = s * 32 + (ln >> 4) * 8 + e;
            int c = n * 16 + (ln & 15);
            w1a_r[idx] = (c < A) ? w1[k * A + c] : 0.f;
            w1c_r[idx] = (c < A) ? w1[(2 * H + k) * A + c] : 0.f;
        }
    }
}

// Kernel 2: 800 blocks; wave w owns i1 = 4*bg+w (0..99) and i2 = 199-i1 (100..199).
// Constant work/wave (~14 m-iters). One shared m-loop: tile B-fragments and PV
// h-reads are loaded ONCE and feed both i's. Single barrier; single residency round.
__global__ __launch_bounds__(256, 4) void score_kernel(
    const float* __restrict__ h, const short* __restrict__ hb16,
    const float* __restrict__ cc, const float* __restrict__ w1a_r,
    const float* __restrict__ w1c_r, const float* __restrict__ b1,
    const float* __restrict__ w2, const float* __restrict__ b2,
    float* __restrict__ out)
{
    int blk = blockIdx.x;
    int b  = blk / 25;
    int bg = blk - b * 25;
    int wave = threadIdx.x >> 6;
    int lane = threadIdx.x & 63;
    int i1 = __builtin_amdgcn_readfirstlane(bg * 4 + wave);
    int i2 = 199 - i1;
    int l15 = lane & 15, l4 = lane >> 4;

    __shared__ __align__(16) short tile[208 * 64];  // pre-swizzled rows
    __shared__ __align__(16) float slds[4][2][16];

    const short* hb16b = hb16 + (size_t)b * L * H;

    // ---- stage only the rows this block needs: 0 .. (199-4bg | 15) ----
    int i2max = 199 - 4 * bg;
    int nch = (((i2max | 15) + 1) + 7) >> 3;        // chunks of 8 rows
    for (int c = wave; c < nch; c += 4) {
        int j = c * 8 + (lane >> 3); if (j > L - 1) j = L - 1;
        const short* src = hb16b + (size_t)j * H + (lane & 7) * 8;
        __builtin_amdgcn_global_load_lds(
            (const __attribute__((address_space(1))) void*)src,
            (__attribute__((address_space(3))) void*)&tile[c * 512],
            16, 0, 0);
    }

    // ---- prologue (overlaps staging): constants + A-fragments for both i's ----
    float b2v = b2[0];
    float w2v[3][4];
    #pragma unroll
    for (int n = 0; n < 3; ++n) {
        #pragma unroll
        for (int r = 0; r < 4; ++r) {
            int a = n * 16 + l4 * 4 + r;
            w2v[n][r] = (a < A) ? w2[a] : 0.f;
        }
    }
    float cbv[2][3][4];
    short8 afrag[2][2][3];                          // [ii][s][n]
    int iv[2] = {i1, i2};
    #pragma unroll
    for (int ii = 0; ii < 2; ++ii) {
        const float* hi    = h + ((size_t)b * L + iv[ii]) * H;   // uniform -> s_load
        const float* ccrow = cc + ((size_t)b * L + iv[ii]) * A;
        #pragma unroll
        for (int n = 0; n < 3; ++n) {
            #pragma unroll
            for (int r = 0; r < 4; ++r) {
                int a = n * 16 + l4 * 4 + r;
                cbv[ii][n][r] = (a < A) ? (ccrow[a] + b1[a]) : 0.f;
            }
        }
        #pragma unroll
        for (int s = 0; s < 2; ++s) {
            float hik[8];
            #pragma unroll
            for (int e = 0; e < 8; ++e) hik[e] = hi[s * 32 + l4 * 8 + e];
            #pragma unroll
            for (int n = 0; n < 3; ++n) {
                floatx8 wa = *(const floatx8*)&w1a_r[(((s * 3 + n) * 64) + lane) * 8];
                floatx8 wc = *(const floatx8*)&w1c_r[(((s * 3 + n) * 64) + lane) * 8];
                #pragma unroll
                for (int e = 0; e < 8; ++e)
                    afrag[ii][s][n][e] = f2bf(fmaf(hik[e], wc[e], wa[e]));
            }
        }
    }
    __syncthreads();   // staging complete

    float oacc1[4] = {0.f, 0.f, 0.f, 0.f};
    float oacc2[4] = {0.f, 0.f, 0.f, 0.f};
    int mmax1 = (i1 >> 4) + 1;
    int mmax2 = (i2 >> 4) + 1;   // >= mmax1 always (i2 >= 100 > i1)

    for (int m = 0; m < mmax2; ++m) {
        int row = m * 16 + l15;                      // j for this lane's B-column
        const short* brow = tile + row * 64;
        int sw = (l15 & 7) << 3;
        short8 bf0 = *(const short8*)(brow + ((l4 * 8) ^ sw));
        short8 bf1 = *(const short8*)(brow + ((32 + l4 * 8) ^ sw));
        bool do1 = (m < mmax1);                      // wave-uniform

        // ---- i2 MFMAs ----
        floatx4 d0 = {cbv[1][0][0], cbv[1][0][1], cbv[1][0][2], cbv[1][0][3]};
        floatx4 d1 = {cbv[1][1][0], cbv[1][1][1], cbv[1][1][2], cbv[1][1][3]};
        floatx4 d2 = {cbv[1][2][0], cbv[1][2][1], cbv[1][2][2], cbv[1][2][3]};
        d0 = __builtin_amdgcn_mfma_f32_16x16x32_bf16(afrag[1][0][0], bf0, d0, 0, 0, 0);
        d1 = __builtin_amdgcn_mfma_f32_16x16x32_bf16(afrag[1][0][1], bf0, d1, 0, 0, 0);
        d2 = __builtin_amdgcn_mfma_f32_16x16x32_bf16(afrag[1][0][2], bf0, d2, 0, 0, 0);
        d0 = __builtin_amdgcn_mfma_f32_16x16x32_bf16(afrag[1][1][0], bf1, d0, 0, 0, 0);
        d1 = __builtin_amdgcn_mfma_f32_16x16x32_bf16(afrag[1][1][1], bf1, d1, 0, 0, 0);
        d2 = __builtin_amdgcn_mfma_f32_16x16x32_bf16(afrag[1][1][2], bf1, d2, 0, 0, 0);
        {   // epilogue i2
            float sp = 0.f;
            #pragma unroll
            for (int r = 0; r < 4; ++r) {
                float v0 = d0[r], v1 = d1[r], v2 = d2[r];
                float a0 = fmaf(0.01f, fminf(v0, 0.f), fmaxf(v0, 0.f));
                float a1 = fmaf(0.01f, fminf(v1, 0.f), fmaxf(v1, 0.f));
                float a2 = fmaf(0.01f, fminf(v2, 0.f), fmaxf(v2, 0.f));
                sp = fmaf(a0, w2v[0][r], sp);
                sp = fmaf(a1, w2v[1][r], sp);
                sp = fmaf(a2, w2v[2][r], sp);
            }
            sp += __shfl_xor(sp, 16, 64);
            sp += __shfl_xor(sp, 32, 64);
            float sc = (row <= i2) ? sp + b2v : 0.f;
            if (l4 == 0) slds[wave][1][l15] = sc;
        }
        if (do1) {
            floatx4 e0 = {cbv[0][0][0], cbv[0][0][1], cbv[0][0][2], cbv[0][0][3]};
            floatx4 e1 = {cbv[0][1][0], cbv[0][1][1], cbv[0][1][2], cbv[0][1][3]};
            floatx4 e2 = {cbv[0][2][0], cbv[0][2][1], cbv[0][2][2], cbv[0][2][3]};
            e0 = __builtin_amdgcn_mfma_f32_16x16x32_bf16(afrag[0][0][0], bf0, e0, 0, 0, 0);
            e1 = __builtin_amdgcn_mfma_f32_16x16x32_bf16(afrag[0][0][1], bf0, e1, 0, 0, 0);
            e2 = __builtin_amdgcn_mfma_f32_16x16x32_bf16(afrag[0][0][2], bf0, e2, 0, 0, 0);
            e0 = __builtin_amdgcn_mfma_f32_16x16x32_bf16(afrag[0][1][0], bf1, e0, 0, 0, 0);
            e1 = __builtin_amdgcn_mfma_f32_16x16x32_bf16(afrag[0][1][1], bf1, e1, 0, 0, 0);
            e2 = __builtin_amdgcn_mfma_f32_16x16x32_bf16(afrag[0][1][2], bf1, e2, 0, 0, 0);
            float sp = 0.f;
            #pragma unroll
            for (int r = 0; r < 4; ++r) {
                float v0 = e0[r], v1 = e1[r], v2 = e2[r];
                float a0 = fmaf(0.01f, fminf(v0, 0.f), fmaxf(v0, 0.f));
                float a1 = fmaf(0.01f, fminf(v1, 0.f), fmaxf(v1, 0.f));
                float a2 = fmaf(0.01f, fminf(v2, 0.f), fmaxf(v2, 0.f));
                sp = fmaf(a0, w2v[0][r], sp);
                sp = fmaf(a1, w2v[1][r], sp);
                sp = fmaf(a2, w2v[2][r], sp);
            }
            sp += __shfl_xor(sp, 16, 64);
            sp += __shfl_xor(sp, 32, 64);
            float sc = (row <= i1) ? sp + b2v : 0.f;
            if (l4 == 0) slds[wave][0][l15] = sc;
        }

        // ---- PV: shared tile reads feed both accumulators ----
        #pragma unroll
        for (int rb = 0; rb < 4; ++rb) {
            floatx4 sv2 = *(const floatx4*)&slds[wave][1][rb * 4];  // same-wave RAW
            floatx4 sv1;
            if (do1) sv1 = *(const floatx4*)&slds[wave][0][rb * 4];
            #pragma unroll
            for (int q = 0; q < 4; ++q) {
                int j = m * 16 + rb * 4 + q;
                float hv = bf2f(tile[j * 64 + (lane ^ ((j & 7) << 3))]);
                oacc2[q] = fmaf(sv2[q], hv, oacc2[q]);
                if (do1) oacc1[q] = fmaf(sv1[q], hv, oacc1[q]);
            }
        }
    }

    out[((size_t)b * L + i1) * H + lane] = (oacc1[0] + oacc1[1]) + (oacc1[2] + oacc1[3]);
    out[((size_t)b * L + i2) * H + lane] = (oacc2[0] + oacc2[1]) + (oacc2[2] + oacc2[3]);
}

extern "C" void kernel_launch(void* const* d_in, const int* in_sizes, int n_in,
                              void* d_out, int out_size, void* d_ws, size_t ws_size,
                              hipStream_t stream) {
    const float* x    = (const float*)d_in[0];
    const float* ln_w = (const float*)d_in[1];
    const float* ln_b = (const float*)d_in[2];
    const float* w1   = (const float*)d_in[3];
    const float* b1   = (const float*)d_in[4];
    const float* w2   = (const float*)d_in[5];
    const float* b2   = (const float*)d_in[6];
    float* out = (float*)d_out;

    float* h_ws   = (float*)d_ws;                             // B*L*H f32
    float* cc_ws  = h_ws + (size_t)B * L * H;                 // B*L*A f32
    short* hb16_ws = (short*)(cc_ws + (size_t)B * L * A);     // B*L*H bf16 (pre-swizzled)
    float* w1a_r  = (float*)(hb16_ws + (size_t)B * L * H);    // 3072 f32
    float* w1c_r  = w1a_r + 3072;                             // 3072 f32

    prep_kernel<<<(B * L) / 4, 256, 0, stream>>>(x, ln_w, ln_b, w1, h_ws, cc_ws,
                                                 hb16_ws, w1a_r, w1c_r);
    score_kernel<<<B * 25, 256, 0, stream>>>(h_ws, hb16_ws, cc_ws, w1a_r, w1c_r,
                                             b1, w2, b2, out);
}

// Round 8
// 37.688 us; speedup vs baseline: 1.8863x; 1.8863x over previous
//
#include <hip/hip_runtime.h>

#define B 32
#define L 200
#define DIN 64
#define H 64
#define A 36

typedef __attribute__((ext_vector_type(8))) short short8;   // bf16 MFMA fragment
typedef __attribute__((ext_vector_type(4))) float floatx4;  // MFMA accumulator
typedef __attribute__((ext_vector_type(8))) float floatx8;

static __device__ __forceinline__ short f2bf(float f) {
    union { float f; unsigned u; } v; v.f = f;
    unsigned r = (v.u + 0x7FFF + ((v.u >> 16) & 1)) >> 16;  // RNE
    return (short)r;
}

// Kernel 1: h = x@ln_w + ln_b ; h f32, hb16 pre-swizzled, cc = h@w1b.
// Block 0 also reorders w1a/w1c into MFMA-fragment order (f32).
__global__ __launch_bounds__(256) void prep_kernel(
    const float* __restrict__ x, const float* __restrict__ ln_w,
    const float* __restrict__ ln_b, const float* __restrict__ w1,
    float* __restrict__ h_out, float* __restrict__ cc_out, short* __restrict__ hb16_out,
    float* __restrict__ w1a_r, float* __restrict__ w1c_r)
{
    int wave = threadIdx.x >> 6;
    int lane = threadIdx.x & 63;
    int bl = __builtin_amdgcn_readfirstlane(blockIdx.x * 4 + wave);
    const float* xr = x + (size_t)bl * DIN;
    float p0 = ln_b[lane], p1 = 0.f;
    #pragma unroll
    for (int d = 0; d < DIN; d += 2) {
        p0 = fmaf(xr[d],     ln_w[d * H + lane],       p0);   // xr uniform -> s_load
        p1 = fmaf(xr[d + 1], ln_w[(d + 1) * H + lane], p1);
    }
    float acc = p0 + p1;
    __shared__ float hrow[4][H];
    hrow[wave][lane] = acc;
    h_out[(size_t)bl * H + lane] = acc;
    int j = bl % L;
    hb16_out[(size_t)bl * H + (lane ^ ((j & 7) << 3))] = f2bf(acc);
    if (lane < A) {
        float s0 = 0.f, s1 = 0.f;
        #pragma unroll
        for (int hh = 0; hh < H; hh += 2) {
            s0 = fmaf(hrow[wave][hh],     w1[(H + hh) * A + lane],     s0);   // w1b
            s1 = fmaf(hrow[wave][hh + 1], w1[(H + hh + 1) * A + lane], s1);
        }
        cc_out[(size_t)bl * A + lane] = s0 + s1;
    }
    if (blockIdx.x == 0) {
        // fragment-order tables: idx = ((s*3+n)*64 + lane)*8 + e
        for (int idx = threadIdx.x; idx < 2 * 3 * 64 * 8; idx += 256) {
            int e = idx & 7, ln = (idx >> 3) & 63, sn = idx >> 9;
            int s = sn / 3, n = sn - 3 * s;
            int k = s * 32 + (ln >> 4) * 8 + e;
            int c = n * 16 + (ln & 15);
            w1a_r[idx] = (c < A) ? w1[k * A + c] : 0.f;
            w1c_r[idx] = (c < A) ? w1[(2 * H + k) * A + c] : 0.f;
        }
    }
}

// Kernel 2: block=(b,bg), bg 0..49; wave w owns i = bg + 50w. All 200 rows staged
// once (global_load_lds w16, pre-swizzled); one barrier.
// LDS pipe carries ONLY the 2 B-fragment ds_read_b128 per m-iter:
//  - score broadcast via v_readlane (SGPR), no slds round-trip
//  - PV reads f32 h from global (coalesced dword, L1/L2-hot) on the VMEM pipe
__global__ __launch_bounds__(256) void score_kernel(
    const float* __restrict__ h, const short* __restrict__ hb16,
    const float* __restrict__ cc, const float* __restrict__ w1a_r,
    const float* __restrict__ w1c_r, const float* __restrict__ b1,
    const float* __restrict__ w2, const float* __restrict__ b2,
    float* __restrict__ out)
{
    int blk = blockIdx.x;
    int b  = blk / 50;
    int bg = blk - b * 50;
    int wave = threadIdx.x >> 6;
    int lane = threadIdx.x & 63;
    int i = __builtin_amdgcn_readfirstlane(bg + 50 * wave);
    int l15 = lane & 15, l4 = lane >> 4;

    __shared__ __align__(16) short tile[208 * 64];  // 200 rows + 8 pad, pre-swizzled

    const short* hb16b = hb16 + (size_t)b * L * H;

    // ---- stage: 26 chunks x 8 rows, global_load_lds width 16 ----
    for (int c = wave; c < 26; c += 4) {
        int j = (c < 25) ? (c * 8 + (lane >> 3)) : (L - 1);   // pad rows: row-199 data
        const short* src = hb16b + (size_t)j * H + (lane & 7) * 8;
        __builtin_amdgcn_global_load_lds(
            (const __attribute__((address_space(1))) void*)src,
            (__attribute__((address_space(3))) void*)&tile[c * 512],
            16, 0, 0);
    }

    // ---- prologue (overlaps staging) ----
    const float* hi    = h + ((size_t)b * L + i) * H;     // uniform -> s_load
    const float* ccrow = cc + ((size_t)b * L + i) * A;
    float b2v = b2[0];
    float w2v[3][4], cbv[3][4];
    #pragma unroll
    for (int n = 0; n < 3; ++n) {
        #pragma unroll
        for (int r = 0; r < 4; ++r) {
            int a = n * 16 + l4 * 4 + r;       // this lane's C row for tile n, reg r
            bool av = a < A;
            w2v[n][r] = av ? w2[a] : 0.f;
            cbv[n][r] = av ? (ccrow[a] + b1[a]) : 0.f;
        }
    }
    short8 afrag[2][3];                        // A-operand: B_i[a = n*16+l15][k]
    #pragma unroll
    for (int s = 0; s < 2; ++s) {
        float hik[8];
        #pragma unroll
        for (int e = 0; e < 8; ++e) hik[e] = hi[s * 32 + l4 * 8 + e];
        #pragma unroll
        for (int n = 0; n < 3; ++n) {
            floatx8 wa = *(const floatx8*)&w1a_r[(((s * 3 + n) * 64) + lane) * 8];
            floatx8 wc = *(const floatx8*)&w1c_r[(((s * 3 + n) * 64) + lane) * 8];
            #pragma unroll
            for (int e = 0; e < 8; ++e)
                afrag[s][n][e] = f2bf(fmaf(hik[e], wc[e], wa[e]));
        }
    }
    __syncthreads();   // staging complete

    float oacc[4] = {0.f, 0.f, 0.f, 0.f};
    int mmax = (i >> 4) + 1;   // wave-uniform

    for (int m = 0; m < mmax; ++m) {
        // B-fragment: h[j = m*16+l15][k], swizzled read (only LDS ops in the loop)
        int row = m * 16 + l15;
        const short* brow = tile + row * 64;
        int sw = (l15 & 7) << 3;
        short8 bf0 = *(const short8*)(brow + ((l4 * 8) ^ sw));
        short8 bf1 = *(const short8*)(brow + ((32 + l4 * 8) ^ sw));
        floatx4 c0 = {cbv[0][0], cbv[0][1], cbv[0][2], cbv[0][3]};
        floatx4 c1 = {cbv[1][0], cbv[1][1], cbv[1][2], cbv[1][3]};
        floatx4 c2 = {cbv[2][0], cbv[2][1], cbv[2][2], cbv[2][3]};
        c0 = __builtin_amdgcn_mfma_f32_16x16x32_bf16(afrag[0][0], bf0, c0, 0, 0, 0);
        c1 = __builtin_amdgcn_mfma_f32_16x16x32_bf16(afrag[0][1], bf0, c1, 0, 0, 0);
        c2 = __builtin_amdgcn_mfma_f32_16x16x32_bf16(afrag[0][2], bf0, c2, 0, 0, 0);
        c0 = __builtin_amdgcn_mfma_f32_16x16x32_bf16(afrag[1][0], bf1, c0, 0, 0, 0);
        c1 = __builtin_amdgcn_mfma_f32_16x16x32_bf16(afrag[1][1], bf1, c1, 0, 0, 0);
        c2 = __builtin_amdgcn_mfma_f32_16x16x32_bf16(afrag[1][2], bf1, c2, 0, 0, 0);
        // epilogue: leaky = max(x, 0.01x); 3 independent w2-dot chains; 2 shfl rounds
        float sp0 = 0.f, sp1 = 0.f, sp2 = 0.f;
        #pragma unroll
        for (int r = 0; r < 4; ++r) {
            sp0 = fmaf(fmaxf(c0[r], 0.01f * c0[r]), w2v[0][r], sp0);
            sp1 = fmaf(fmaxf(c1[r], 0.01f * c1[r]), w2v[1][r], sp1);
            sp2 = fmaf(fmaxf(c2[r], 0.01f * c2[r]), w2v[2][r], sp2);
        }
        float sp = (sp0 + sp1) + sp2;
        sp += __shfl_xor(sp, 16, 64);
        sp += __shfl_xor(sp, 32, 64);          // all lanes: full a-sum for j = m*16+l15
        float sc = (row <= i) ? sp + b2v : 0.f;

        // PV: coalesced f32 global reads of h rows; score via readlane (SGPR)
        const float* hjb = h + ((size_t)b * L + m * 16) * H + lane;
        #pragma unroll
        for (int rb = 0; rb < 4; ++rb) {
            #pragma unroll
            for (int q = 0; q < 4; ++q) {
                int jq = rb * 4 + q;
                float sq = __int_as_float(
                    __builtin_amdgcn_readlane(__float_as_int(sc), jq));
                float hv = hjb[jq * H];        // dword, imm offset, L1/L2-hot
                oacc[rb] = fmaf(sq, hv, oacc[rb]);
            }
        }
    }

    out[((size_t)b * L + i) * H + lane] = (oacc[0] + oacc[1]) + (oacc[2] + oacc[3]);
}

extern "C" void kernel_launch(void* const* d_in, const int* in_sizes, int n_in,
                              void* d_out, int out_size, void* d_ws, size_t ws_size,
                              hipStream_t stream) {
    const float* x    = (const float*)d_in[0];
    const float* ln_w = (const float*)d_in[1];
    const float* ln_b = (const float*)d_in[2];
    const float* w1   = (const float*)d_in[3];
    const float* b1   = (const float*)d_in[4];
    const float* w2   = (const float*)d_in[5];
    const float* b2   = (const float*)d_in[6];
    float* out = (float*)d_out;

    float* h_ws   = (float*)d_ws;                             // B*L*H f32
    float* cc_ws  = h_ws + (size_t)B * L * H;                 // B*L*A f32
    short* hb16_ws = (short*)(cc_ws + (size_t)B * L * A);     // B*L*H bf16 (pre-swizzled)
    float* w1a_r  = (float*)(hb16_ws + (size_t)B * L * H);    // 3072 f32
    float* w1c_r  = w1a_r + 3072;                             // 3072 f32

    prep_kernel<<<(B * L) / 4, 256, 0, stream>>>(x, ln_w, ln_b, w1, h_ws, cc_ws,
                                                 hb16_ws, w1a_r, w1c_r);
    score_kernel<<<B * 50, 256, 0, stream>>>(h_ws, hb16_ws, cc_ws, w1a_r, w1c_r,
                                             b1, w2, b2, out);
}